// Round 9
// baseline (76.241 us; speedup 1.0000x reference)
//
#include <hip/hip_runtime.h>

typedef _Float16 f16;
typedef _Float16 f16x4 __attribute__((ext_vector_type(4)));
typedef _Float16 n16x2 __attribute__((ext_vector_type(2)));
typedef float    f32x4 __attribute__((ext_vector_type(4)));

#define LOG2E 1.44269504088896340736f
#define OFF25 36.0673760222824936f   /* 25 * log2(e) */

__device__ __forceinline__ f32x4 MFMA(f16x4 a, f16x4 b, f32x4 c) {
#if defined(__HIP_DEVICE_COMPILE__)
    return __builtin_amdgcn_mfma_f32_16x16x16f16(a, b, c, 0, 0, 0);
#else
    return c;   // host parse stub — never executed
#endif
}

__device__ __forceinline__ float fexp2(float x) {
#if defined(__HIP_DEVICE_COMPILE__)
    return __builtin_amdgcn_exp2f(x);
#else
    return exp2f(x);
#endif
}

__device__ __forceinline__ f16x4 pk4(float a, float b, float c, float d) {
#if defined(__HIP_DEVICE_COMPILE__)
    n16x2 lo = __builtin_bit_cast(n16x2, __builtin_amdgcn_cvt_pkrtz(a, b));
    n16x2 hi = __builtin_bit_cast(n16x2, __builtin_amdgcn_cvt_pkrtz(c, d));
    f16x4 r; r[0] = lo[0]; r[1] = lo[1]; r[2] = hi[0]; r[3] = hi[1];
    return r;
#else
    f16x4 r; r[0] = (f16)a; r[1] = (f16)b; r[2] = (f16)c; r[3] = (f16)d;
    return r;
#endif
}

// ---------------------------------------------------------------------------
// K1: projections, K-split (unchanged from round 8).
// ---------------------------------------------------------------------------
__global__ __launch_bounds__(256) void k_proj(const float* __restrict__ x,
        const float* __restrict__ wf, const float* __restrict__ wg,
        const float* __restrict__ wh, f16* __restrict__ F,
        f16* __restrict__ G, float* __restrict__ Ht) {
    const int lane = threadIdx.x & 63;
    const int wid  = threadIdx.x >> 6;
    const int tile = wid >> 1;
    const int kh   = wid & 1;
    const int g16  = lane >> 4;
    const int c16  = lane & 15;
    const long r0  = ((long)blockIdx.x * 2 + tile) * 16;

    f16x4 bw[3][4];
    const float* Ws[3] = { wf, wg, wh };
    #pragma unroll
    for (int w = 0; w < 3; ++w)
        #pragma unroll
        for (int kk = 0; kk < 4; ++kk) {
            const int kb = (kh * 4 + kk) * 16 + g16 * 4;
            bw[w][kk] = pk4(Ws[w][(kb + 0) * 16 + c16], Ws[w][(kb + 1) * 16 + c16],
                            Ws[w][(kb + 2) * 16 + c16], Ws[w][(kb + 3) * 16 + c16]);
        }

    f32x4 af = {0,0,0,0}, ag = {0,0,0,0}, ah = {0,0,0,0};
    const float* xr = x + (r0 + c16) * 128;
    #pragma unroll
    for (int kk = 0; kk < 4; ++kk) {
        float4 xa = *(const float4*)(xr + (kh * 4 + kk) * 16 + g16 * 4);
        f16x4 a = pk4(xa.x, xa.y, xa.z, xa.w);
        af = MFMA(a, bw[0][kk], af);
        ag = MFMA(a, bw[1][kk], ag);
        ah = MFMA(a, bw[2][kk], ah);
    }

    __shared__ float red[2][64][13];
    if (kh == 1) {
        #pragma unroll
        for (int i = 0; i < 4; ++i) {
            red[tile][lane][i]     = af[i];
            red[tile][lane][4 + i] = ag[i];
            red[tile][lane][8 + i] = ah[i];
        }
    }
    __syncthreads();
    if (kh == 0) {
        #pragma unroll
        for (int i = 0; i < 4; ++i) {
            af[i] += red[tile][lane][i];
            ag[i] += red[tile][lane][4 + i];
            ah[i] += red[tile][lane][8 + i];
        }
        #pragma unroll
        for (int i = 0; i < 4; ++i) {
            const long row = r0 + g16 * 4 + i;
            F[row * 16 + c16] = (f16)af[i];
            G[row * 16 + c16] = (f16)ag[i];
        }
        float4 hv = make_float4(ah[0], ah[1], ah[2], ah[3]);
        *(float4*)(Ht + (long)c16 * 32768 + r0 + g16 * 4) = hv;
    }
}

// ---------------------------------------------------------------------------
// K2: column stats + fused Hs scaling, LDS-staged F stream.
// Block = 64 m (ga[4]/wave in regs); F streamed in 128-n chunks through
// double-buffered LDS; wave w consumes n-tile w of each chunk (broadcast).
// ---------------------------------------------------------------------------
__global__ __launch_bounds__(512) void k_cs(const f16* __restrict__ F,
        const f16* __restrict__ G, const float* __restrict__ Ht,
        float* __restrict__ nM2, f16* __restrict__ Hs) {
    const int lane = threadIdx.x & 63;
    const int wid  = threadIdx.x >> 6;               // 0..7 = n-tile in chunk
    const int b    = blockIdx.x >> 6;
    const int mb   = (blockIdx.x & 63) * 64;
    const int g16  = lane >> 4, c16 = lane & 15;
    const long bb  = (long)b * 4096;

    f16x4 ga[4];
    #pragma unroll
    for (int j = 0; j < 4; ++j)
        ga[j] = *(const f16x4*)(G + (bb + mb + 16 * j + c16) * 16 + g16 * 4);

    __shared__ f16 fld[2][128][16];                  // 8 KB double buffer
    const f16* Fb = F + bb * 16;
    // staging assignment: thread i -> row i>>2, cols (i&3)*4
    const int sr = threadIdx.x >> 2, sc = (threadIdx.x & 3) * 4;

    float qm[4][4], zs[4][4];
    #pragma unroll
    for (int j = 0; j < 4; ++j)
        #pragma unroll
        for (int i = 0; i < 4; ++i) { qm[j][i] = -1e30f; zs[j][i] = 0.f; }

    f16x4 r = *(const f16x4*)(Fb + (0 * 128 + sr) * 16 + sc);
    *(f16x4*)&fld[0][sr][sc] = r;
    r = *(const f16x4*)(Fb + (1 * 128 + sr) * 16 + sc);

    for (int t = 0; t < 32; ++t) {
        __syncthreads();
        if (t + 1 < 32) *(f16x4*)&fld[(t + 1) & 1][sr][sc] = r;
        if (t + 2 < 32) r = *(const f16x4*)(Fb + ((t + 2) * 128 + sr) * 16 + sc);
        f16x4 fb = *(const f16x4*)&fld[t & 1][wid * 16 + c16][g16 * 4];
        #pragma unroll
        for (int j = 0; j < 4; ++j) {
            f32x4 zero = {0,0,0,0};
            f32x4 s = MFMA(ga[j], fb, zero);
            #pragma unroll
            for (int i = 0; i < 4; ++i) {
                const float q = fmaf(s[i], LOG2E, -OFF25);
                zs[j][i] += fexp2(q);
                qm[j][i] = fmaxf(qm[j][i], q);
            }
        }
    }
    #pragma unroll
    for (int d = 8; d >= 1; d >>= 1)
        #pragma unroll
        for (int j = 0; j < 4; ++j)
            #pragma unroll
            for (int i = 0; i < 4; ++i) {
                qm[j][i] = fmaxf(qm[j][i], __shfl_xor(qm[j][i], d));
                zs[j][i] += __shfl_xor(zs[j][i], d);
            }

    __shared__ float lq[8][64], lz[8][64], lrz[64];
    if (c16 == 0) {
        #pragma unroll
        for (int j = 0; j < 4; ++j)
            #pragma unroll
            for (int i = 0; i < 4; ++i) {
                const int ml = 16 * j + 4 * g16 + i;
                lq[wid][ml] = qm[j][i];
                lz[wid][ml] = zs[j][i];
            }
    }
    __syncthreads();
    if (threadIdx.x < 64) {
        const int ml = threadIdx.x;
        float q = lq[0][ml], z = 0.f;
        #pragma unroll
        for (int p = 1; p < 8; ++p) q = fmaxf(q, lq[p][ml]);
        #pragma unroll
        for (int p = 0; p < 8; ++p) z += lz[p][ml];
        nM2[bb + mb + ml] = -q - OFF25;
        lrz[ml] = fexp2(q) / z;
    }
    __syncthreads();
    #pragma unroll
    for (int rr = 0; rr < 2; ++rr) {
        const int d = wid * 2 + rr;
        const long a = (long)d * 32768 + bb + mb + lane;
        Hs[a] = (f16)(Ht[a] * lrz[lane]);
    }
}

// ---------------------------------------------------------------------------
// K3: PV + fused output projection, LDS-staged m-stream.
// Block = 64 n-rows; 8 waves = 2 groups x 4 n-tiles.  Wave owns one n-tile
// (F-frag in regs); group g streams m-half g in 64-m chunks via LDS
// (G-slice, XOR-swizzled Hs^T-slice, nM).  2-way cross-group reduce, then
// fused (Y @ gamma*w_v) + x epilogue (col-halves split by group).
// ---------------------------------------------------------------------------
__global__ __launch_bounds__(512) void k_pv(const f16* __restrict__ F,
        const f16* __restrict__ G, const f16* __restrict__ Hs,
        const float* __restrict__ nM2, const float* __restrict__ wv,
        const float* __restrict__ xin, const float* __restrict__ gamma,
        float* __restrict__ out) {
    const int lane = threadIdx.x & 63;
    const int wid  = threadIdx.x >> 6;               // 0..7
    const int g    = wid >> 2;                       // m-half
    const int j    = wid & 3;                        // n-tile within block
    const int ltid = threadIdx.x & 255;              // tid within group
    const int b    = blockIdx.x >> 6;
    const int n0   = (blockIdx.x & 63) * 64;
    const int g16  = lane >> 4, c16 = lane & 15;
    const long bb  = (long)b * 4096;

    const f16x4 fbv = *(const f16x4*)(F + (bb + n0 + 16 * j + c16) * 16 + g16 * 4);

    const float gm = gamma[0];
    f16x4 wvf[4];
    #pragma unroll
    for (int t = 0; t < 4; ++t) {
        const int c0 = (g * 4 + t) * 16;
        wvf[t] = pk4(wv[(g16 * 4 + 0) * 128 + c0 + c16] * gm,
                     wv[(g16 * 4 + 1) * 128 + c0 + c16] * gm,
                     wv[(g16 * 4 + 2) * 128 + c0 + c16] * gm,
                     wv[(g16 * 4 + 3) * 128 + c0 + c16] * gm);
    }

    __shared__ f16   gld[2][2][64][16];              // [g][buf] G-slice, 8 KB
    __shared__ f16   hld[2][2][16][64];              // [g][buf] Hs^T swizzled, 8 KB
    __shared__ float nmld[2][2][64];                 // [g][buf] nM2 slice, 1 KB

    const int mbase = g * 2048;
    // staging assignment within group (256 threads):
    const int gsr = ltid >> 2, gsc = (ltid & 3) * 4;         // G: row, col4
    const int hd  = ltid >> 4, hml = (ltid & 15) * 4;        // Hs: d, m4
    const int hsw = hml ^ ((hd & 15) * 4);                   // swizzled col
    const f16* Gp = G + bb * 16;
    const f16* Hp = Hs + (long)hd * 32768 + bb + mbase;
    const float* Np = nM2 + bb + mbase;

    f16x4 rg, rh; float rn;
    // prologue: chunk 0 -> buf 0, preload chunk 1
    rg = *(const f16x4*)(Gp + (mbase + gsr) * 16 + gsc);
    rh = *(const f16x4*)(Hp + hml);
    *(f16x4*)&gld[g][0][gsr][gsc] = rg;
    *(f16x4*)&hld[g][0][hd][hsw]  = rh;
    if (ltid < 64) nmld[g][0][ltid] = Np[ltid];
    rg = *(const f16x4*)(Gp + (mbase + 64 + gsr) * 16 + gsc);
    rh = *(const f16x4*)(Hp + 64 + hml);
    rn = (ltid < 64) ? Np[64 + ltid] : 0.f;

    f32x4 yT = {0,0,0,0};
    for (int t = 0; t < 32; ++t) {
        __syncthreads();
        if (t + 1 < 32) {
            *(f16x4*)&gld[g][(t + 1) & 1][gsr][gsc] = rg;
            *(f16x4*)&hld[g][(t + 1) & 1][hd][hsw]  = rh;
            if (ltid < 64) nmld[g][(t + 1) & 1][ltid] = rn;
        }
        if (t + 2 < 32) {
            const int mo = (t + 2) * 64;
            rg = *(const f16x4*)(Gp + (mbase + mo + gsr) * 16 + gsc);
            rh = *(const f16x4*)(Hp + mo + hml);
            rn = (ltid < 64) ? Np[mo + ltid] : 0.f;
        }
        const int cur = t & 1;
        #pragma unroll
        for (int mt = 0; mt < 4; ++mt) {
            f16x4 ga = *(const f16x4*)&gld[g][cur][mt * 16 + c16][g16 * 4];
            f16x4 ha = *(const f16x4*)&hld[g][cur][c16][(mt * 16 + g16 * 4) ^ (c16 * 4)];
            f32x4 nm = *(const f32x4*)&nmld[g][cur][mt * 16 + g16 * 4];
            f32x4 zero = {0,0,0,0};
            f32x4 s = MFMA(ga, fbv, zero);
            f16x4 pb = pk4(fexp2(fmaf(s[0], LOG2E, nm[0])),
                           fexp2(fmaf(s[1], LOG2E, nm[1])),
                           fexp2(fmaf(s[2], LOG2E, nm[2])),
                           fexp2(fmaf(s[3], LOG2E, nm[3])));
            yT = MFMA(ha, pb, yT);
        }
    }

    // 2-way cross-group reduce per n-tile
    __shared__ float red[8][64][5];                  // 10 KB, conflict-free
    #pragma unroll
    for (int i = 0; i < 4; ++i) red[wid][lane][i] = yT[i];
    __syncthreads();
    f32x4 ys;
    #pragma unroll
    for (int i = 0; i < 4; ++i) ys[i] = yT[i] + red[wid ^ 4][lane][i];
    const f16x4 ya = pk4(ys[0], ys[1], ys[2], ys[3]);

    #pragma unroll
    for (int t = 0; t < 4; ++t) {
        const int c0 = (g * 4 + t) * 16;
        f32x4 zero = {0,0,0,0};
        f32x4 o = MFMA(ya, wvf[t], zero);
        #pragma unroll
        for (int i = 0; i < 4; ++i) {
            const long idx = (bb + n0 + 16 * j + 4 * g16 + i) * 128 + c0 + c16;
            out[idx] = o[i] + xin[idx];
        }
    }
}

// ---------------------------------------------------------------------------
extern "C" void kernel_launch(void* const* d_in, const int* in_sizes, int n_in,
                              void* d_out, int out_size, void* d_ws, size_t ws_size,
                              hipStream_t stream) {
    const float* x     = (const float*)d_in[0];
    const float* wf    = (const float*)d_in[1];
    const float* wg    = (const float*)d_in[2];
    const float* wh    = (const float*)d_in[3];
    const float* wv    = (const float*)d_in[4];
    const float* gamma = (const float*)d_in[5];
    float* out = (float*)d_out;

    char* p = (char*)d_ws;
    const long BN  = 8L * 4096;
    const long PAD = 8192;
    f16*   F   = (f16*)p;    p += BN * 16 * sizeof(f16)   + PAD;
    f16*   G   = (f16*)p;    p += BN * 16 * sizeof(f16)   + PAD;
    float* Ht  = (float*)p;  p += 16 * BN * sizeof(float) + PAD;
    f16*   Hs  = (f16*)p;    p += 16 * BN * sizeof(f16)   + PAD;
    float* nM2 = (float*)p;  p += BN * sizeof(float)      + PAD;

    k_proj<<<1024, 256, 0, stream>>>(x, wf, wg, wh, F, G, Ht);
    k_cs  <<<512,  512, 0, stream>>>(F, G, Ht, nM2, Hs);
    k_pv  <<<512,  512, 0, stream>>>(F, G, Hs, nM2, wv, x, gamma, out);
}